// Round 4
// baseline (351.194 us; speedup 1.0000x reference)
//
#include <hip/hip_runtime.h>
#include <hip/hip_bf16.h>

// Problem constants
#define VOCAB 10000
#define HID 256
#define BATCH 32
#define STEPS 256
#define MROWS (STEPS * BATCH)   // 8192

typedef __bf16 bf16x8 __attribute__((ext_vector_type(8)));
typedef float f32x4 __attribute__((ext_vector_type(4)));

// ---------------------------------------------------------------------------
// Kernel 1: transpose + convert W_d [256][10000] f32 -> WdT [10000][256] bf16
// ---------------------------------------------------------------------------
__global__ void transpose_wd_kernel(const float* __restrict__ Wd,
                                    __hip_bfloat16* __restrict__ WdT) {
    __shared__ __hip_bfloat16 tile[64][68];
    const int n0 = blockIdx.x * 64;
    const int k0 = blockIdx.y * 64;
    const int tid = threadIdx.x;
    const int lane = tid & 63;
    const int w = tid >> 6;

#pragma unroll
    for (int i = 0; i < 16; ++i) {
        int k = w * 16 + i;
        int n = lane;
        float v = (n0 + n < VOCAB) ? Wd[(size_t)(k0 + k) * VOCAB + n0 + n] : 0.f;
        tile[n][k] = __float2bfloat16(v);
    }
    __syncthreads();
#pragma unroll
    for (int i = 0; i < 16; ++i) {
        int n = w * 16 + i;
        int k = lane;
        if (n0 + n < VOCAB)
            WdT[(size_t)(n0 + n) * HID + k0 + k] = tile[n][k];
    }
}

// ---------------------------------------------------------------------------
// Kernel 2: gather + RNN recurrence, fp32.
// 32 blocks x 512 threads. Thread (j = tid>>1, q = tid&1) owns half of W_hh
// column j. The weight array is PINNED into VGPRs via empty inline-asm on
// each element: the asm nominally clobbers the value, so the compiler cannot
// rematerialize the loads inside the t-loop (rounds 2-3 failure: VGPR=84/88,
// 128 L2 re-loads/thread/step -> VMEM-issue-bound at ~2000 cy/step).
// h double-buffered in LDS, halves padded so broadcast addresses hit
// different banks (round-3: SQ_LDS_BANK_CONFLICT went to 0). One barrier/step.
// ---------------------------------------------------------------------------
#define HHALF 132   // 128 + 4 pad

__global__ __launch_bounds__(512)
__attribute__((amdgpu_waves_per_eu(2, 2)))
void rnn_kernel(const int* __restrict__ tokens, const float* __restrict__ Wxh,
                const float* __restrict__ Whh, const float* __restrict__ bh,
                const float* __restrict__ h0, __hip_bfloat16* __restrict__ ybf,
                float* __restrict__ state_out) {
    const int b = blockIdx.x;
    const int tid = threadIdx.x;
    const int j = tid >> 1;      // output column 0..255
    const int q = tid & 1;       // k-half

    __shared__ alignas(16) float hbuf[2][2][HHALF];

    // Half-column of W_hh into registers: w[i] = Whh[q*128 + i][j].
    float w[128];
#pragma unroll
    for (int i = 0; i < 128; ++i)
        w[i] = Whh[(size_t)(q * 128 + i) * HID + j];
    // Pin every element in a VGPR; forbids load rematerialization.
#pragma unroll
    for (int i = 0; i < 128; ++i)
        asm volatile("" : "+v"(w[i]));

    if (q == 0) hbuf[0][j >> 7][j & 127] = h0[b * HID + j];
    const float bj = bh[j];
    const int* trow = tokens + b * STEPS;

    // Prefetch step-0 gathered x.
    float x = Wxh[(size_t)trow[0] * HID + j];
    __syncthreads();

    float hn = 0.f;
    int cur = 0;
    for (int t = 0; t < STEPS; ++t) {
        // Prefetch next step's x (hidden under the dot product).
        int tn = (t + 1 < STEPS) ? t + 1 : t;
        float xn = Wxh[(size_t)trow[tn] * HID + j];

        const float* hrow = &hbuf[cur][q][0];
        float a0 = 0.f, a1 = 0.f, a2 = 0.f, a3 = 0.f;
#pragma unroll
        for (int i4 = 0; i4 < 32; ++i4) {
            float4 hv = *reinterpret_cast<const float4*>(&hrow[i4 * 4]);
            a0 += hv.x * w[i4 * 4 + 0];
            a1 += hv.y * w[i4 * 4 + 1];
            a2 += hv.z * w[i4 * 4 + 2];
            a3 += hv.w * w[i4 * 4 + 3];
        }
        float partial = (a0 + a1) + (a2 + a3);
        float sum = partial + __shfl_xor(partial, 1);   // combine k-halves

        // tanh(z) = 1 - 2/(exp(2z)+1)
        float z = x + bj + sum;
        float e = __expf(2.f * z);
        hn = 1.f - 2.f / (e + 1.f);

        if (q == 0)
            hbuf[cur ^ 1][j >> 7][j & 127] = hn;         // next h
        else
            ybf[(size_t)t * (BATCH * HID) + b * HID + j] = __float2bfloat16(hn);

        __syncthreads();
        cur ^= 1;
        x = xn;
    }
    if (q == 0) state_out[b * HID + j] = hn;
}

// ---------------------------------------------------------------------------
// Kernel 3: C[8192][10000] = Y_bf16 @ Wd^T_bf16 + b_d, f32 out. (unchanged;
// no gemm counters captured yet -- top-5 was all rnn. Next round it surfaces.)
// ---------------------------------------------------------------------------
__global__ void gemm_kernel(const __hip_bfloat16* __restrict__ A,   // [8192][256]
                            const __hip_bfloat16* __restrict__ BT,  // [10000][256]
                            const float* __restrict__ bd,
                            float* __restrict__ C) {
    const int n0 = blockIdx.x * 128;
    const int m0 = blockIdx.y * 128;
    const int tid = threadIdx.x;
    const int lane = tid & 63;
    const int wv = tid >> 6;
    const int wr = wv >> 1;
    const int wc = wv & 1;
    const int r15 = lane & 15;
    const int g = lane >> 4;

    __shared__ alignas(16) __hip_bfloat16 As[128][72];
    __shared__ alignas(16) __hip_bfloat16 Bs[128][72];

    f32x4 acc[4][4] = {};

    for (int kb = 0; kb < HID; kb += 64) {
        __syncthreads();
#pragma unroll
        for (int c = 0; c < 4; ++c) {
            int chunk = c * 256 + tid;
            int row = chunk >> 3;
            int cc = chunk & 7;
            bf16x8 av = *reinterpret_cast<const bf16x8*>(
                &A[(size_t)(m0 + row) * HID + kb + cc * 8]);
            *reinterpret_cast<bf16x8*>(&As[row][cc * 8]) = av;

            int nrow = n0 + row;
            bf16x8 bv;
#pragma unroll
            for (int e = 0; e < 8; ++e) bv[e] = (__bf16)0.f;
            if (nrow < VOCAB)
                bv = *reinterpret_cast<const bf16x8*>(
                    &BT[(size_t)nrow * HID + kb + cc * 8]);
            *reinterpret_cast<bf16x8*>(&Bs[row][cc * 8]) = bv;
        }
        __syncthreads();

#pragma unroll
        for (int kk = 0; kk < 64; kk += 32) {
            bf16x8 af[4], bfr[4];
#pragma unroll
            for (int m = 0; m < 4; ++m)
                af[m] = *reinterpret_cast<const bf16x8*>(
                    &As[wr * 64 + m * 16 + r15][kk + g * 8]);
#pragma unroll
            for (int n = 0; n < 4; ++n)
                bfr[n] = *reinterpret_cast<const bf16x8*>(
                    &Bs[wc * 64 + n * 16 + r15][kk + g * 8]);
#pragma unroll
            for (int m = 0; m < 4; ++m)
#pragma unroll
                for (int n = 0; n < 4; ++n)
                    acc[m][n] = __builtin_amdgcn_mfma_f32_16x16x32_bf16(
                        bfr[n], af[m], acc[m][n], 0, 0, 0);
        }
    }

    // Epilogue: element (reg r, lane) = C[m*16 + r15][n*16 + g*4 + r].
#pragma unroll
    for (int m = 0; m < 4; ++m) {
        int row = m0 + wr * 64 + m * 16 + r15;
#pragma unroll
        for (int n = 0; n < 4; ++n) {
            int cb = n0 + wc * 64 + n * 16;      // 16-col frag base
            if (cb + 15 < VOCAB) {               // VOCAB%16==0 -> all-or-nothing
                int col = cb + g * 4;
                float4 bv = *reinterpret_cast<const float4*>(&bd[col]);
                f32x4 v = acc[m][n];
                v[0] += bv.x; v[1] += bv.y; v[2] += bv.z; v[3] += bv.w;
                *reinterpret_cast<f32x4*>(&C[(size_t)row * VOCAB + col]) = v;
            }
        }
    }
}

// ---------------------------------------------------------------------------
extern "C" void kernel_launch(void* const* d_in, const int* in_sizes, int n_in,
                              void* d_out, int out_size, void* d_ws, size_t ws_size,
                              hipStream_t stream) {
    const int* tokens  = (const int*)d_in[0];
    const float* Wxh   = (const float*)d_in[1];
    const float* Whh   = (const float*)d_in[2];
    const float* bh    = (const float*)d_in[3];
    const float* Wd    = (const float*)d_in[4];
    const float* bd    = (const float*)d_in[5];
    const float* h0    = (const float*)d_in[6];

    float* out = (float*)d_out;
    float* state_out = out + (size_t)MROWS * VOCAB;

    __hip_bfloat16* ybf = (__hip_bfloat16*)d_ws;
    __hip_bfloat16* wdt = (__hip_bfloat16*)((char*)d_ws + (size_t)MROWS * HID * 2);

    hipLaunchKernelGGL(transpose_wd_kernel, dim3(157, 4), dim3(256), 0, stream,
                       Wd, wdt);
    hipLaunchKernelGGL(rnn_kernel, dim3(BATCH), dim3(512), 0, stream,
                       tokens, Wxh, Whh, bh, h0, ybf, state_out);
    hipLaunchKernelGGL(gemm_kernel, dim3(79, 64), dim3(256), 0, stream,
                       ybf, wdt, bd, out);
}